// Round 13
// baseline (373.606 us; speedup 1.0000x reference)
//
#include <hip/hip_runtime.h>

// ThermoMHA on MI355X (gfx950).
// Pipeline: prep (cvt x + transpose Wqkv/Wo fused) -> GEMM1 (128x128 m97-style
// tile, scatter to Q/K/Vt fp16, V via LDS transpose; upper-tri zeros of w
// streamed from the K-loop with COUNTED vmcnt, clamped-idempotent scheme,
// per-CU-balanced unit map) -> attn (two-pass, QBLK=64 x 4 waves x 1024
// blocks, swapped-operand QK^T D[key][query], dwordx4 w stores, register-PV;
// LDS-FREE: K/V fragments loaded per-wave directly from global (L2-resident
// panels, 512KB/bh, ~2MB/XCD) -> ZERO barriers, waves fully independent,
// latency hidden by 16 waves/CU TLP) -> GEMM2 (double-buffered LDS, one
// barrier/kt + vmcnt(0)-before-barrier, prefetch kt+1).
// All matmuls: v_mfma_f32_16x16x32_f16, fp32 accum. Softmax fp32 fixed shift
// exp(s-20) via __expf.
//
// NOTE (R3): nontemporal stores regressed. NOTE (R5): zeros in gemm_out
// regressed. NOTE (R8): QBLK=128 regressed (halved per-CU block TLP).
// NOTE (R10/R11): zeros in attn regressed -- attn is latency/sync-bound per
// tile; R13 attacks exactly that by deleting the LDS/barrier pipeline.
//
// Balance map: r -> qt = r<16 ? r : (r<24 ? 39-r : 55-r). Residency sets
// {k, 8+k, 16+k, 24+k} sum to 62 exactly -> per-CU load uniform.

typedef _Float16 half_t;
typedef __attribute__((ext_vector_type(8))) _Float16 h8;
typedef __attribute__((ext_vector_type(4))) _Float16 h4;
typedef __attribute__((ext_vector_type(4))) float f32x4;

#define MFMA(a, b, c) __builtin_amdgcn_mfma_f32_16x16x32_f16(a, b, c, 0, 0, 0)

__device__ __forceinline__ void gload16(const void* g, void* l) {
  __builtin_amdgcn_global_load_lds((const __attribute__((address_space(1))) void*)g,
                                   (__attribute__((address_space(3))) void*)l, 16, 0, 0);
}

__device__ __forceinline__ int balmap(int r) {  // bijection [0,32)->[0,32)
  return (r < 16) ? r : ((r < 24) ? 39 - r : 55 - r);
}

// ---------- fused prep: cvt x (fp32->fp16) + transpose Wqkv, Wo ----------
__global__ __launch_bounds__(256) void prep_kernel(const float* __restrict__ x,
                                                   half_t* __restrict__ xh,
                                                   const float* __restrict__ Wqkv,
                                                   half_t* __restrict__ wqkvt,
                                                   const float* __restrict__ Wo,
                                                   half_t* __restrict__ wot) {
  int b = blockIdx.x;
  if (b >= 1024) {  // cvt x: 1048576 f32x4 over 1024 blocks
    int i = (b - 1024) * 256 + threadIdx.x;
    for (; i < 1048576; i += 262144) {
      f32x4 v = ((const f32x4*)x)[i];
      h4 o;
      o[0] = (half_t)v[0]; o[1] = (half_t)v[1]; o[2] = (half_t)v[2]; o[3] = (half_t)v[3];
      ((h4*)xh)[i] = o;
    }
    return;
  }
  __shared__ float t[64][65];
  int yy = b >> 4;
  const float* in;
  half_t* out;
  int C, c0;
  if (yy < 48) { in = Wqkv; out = wqkvt; C = 3072; c0 = yy * 64; }
  else         { in = Wo;   out = wot;   C = 1024; c0 = (yy - 48) * 64; }
  int r0 = (b & 15) * 64;
  for (int i = threadIdx.x; i < 4096; i += 256) {
    int rr = i >> 6, cc = i & 63;
    t[rr][cc] = in[(size_t)(r0 + rr) * C + (c0 + cc)];
  }
  __syncthreads();
  for (int i = threadIdx.x; i < 4096; i += 256) {
    int rr = i >> 6, cc = i & 63;
    out[(size_t)(c0 + rr) * 1024 + (r0 + cc)] = (half_t)t[cc][rr];
  }
}

// ---------- GEMM1: qkv = xh @ Wqkv (128x128 tile, 4 waves each 64x64).
// Scatters to Q [bh][l][dh], K [bh][l][dh], Vt [bh][dh][l] (via LDS transpose).
// Zero-stream with counted vmcnt (R9 scheme). ----------
__global__ __launch_bounds__(256) void gemm_qkv(const half_t* __restrict__ A,
                                                const half_t* __restrict__ Bt,
                                                half_t* __restrict__ Qb, half_t* __restrict__ Kb,
                                                half_t* __restrict__ Vtb,
                                                float* __restrict__ W) {
  __shared__ __align__(16) char smem[34816];  // mainloop: As 16K + Bs 16K; epi: T 34K
  half_t* As = (half_t*)smem;
  half_t* Bs = As + 8192;
  int bid = blockIdx.x;
  int nt = bid % 24, mt = bid / 24;
  size_t m0 = (size_t)mt * 128, n0 = (size_t)nt * 128;
  int lane = threadIdx.x & 63, wv = threadIdx.x >> 6;
  int wr = wv >> 1, wc = wv & 1;
  int l15 = lane & 15, g = lane >> 4;
  f32x4 acc[4][4] = {};
  f32x4 zf4 = {0.f, 0.f, 0.f, 0.f};

  // zero-stream unit geometry (uniform per block)
  int zbh0 = bid & 31, zqt0 = balmap(bid >> 5);
  int zs0 = (zqt0 + 1) << 6;          // col start (always <= 1536 -> zc0 >= 128)
  int zc0 = (2048 - zs0) >> 2;        // f32x4 count per row
  int u1 = bid + 768;
  int zbh1 = u1 & 31, zqt1 = balmap(u1 >> 5);
  int zs1 = (zqt1 + 1) << 6;
  int zc1 = (2048 - zs1) >> 2;
  bool two_units = (bid < 256) && (zc1 > 0);

  for (int kt = 0; kt < 16; ++kt) {
    __builtin_amdgcn_s_barrier();     // prev MFMA done reading LDS (loads drained last iter)
#pragma unroll
    for (int i = 0; i < 4; ++i) {  // As: 16 chunks of 1KB
      int ch = wv * 4 + i;
      int slot = ch * 64 + lane;
      int row = slot >> 3, s = slot & 7, ss = s ^ (row & 7);
      gload16(A + (m0 + row) * 1024 + kt * 64 + ss * 8, As + ch * 512);
    }
#pragma unroll
    for (int i = 0; i < 4; ++i) {  // Bs: 16 chunks of 1KB
      int ch = wv * 4 + i;
      int slot = ch * 64 + lane;
      int row = slot >> 3, s = slot & 7, ss = s ^ (row & 7);
      gload16(Bt + (n0 + row) * 1024 + kt * 64 + ss * 8, Bs + ch * 512);
    }
    // zero stores: rows kt*4..kt*4+3 of each unit, fixed 8 stores/thread/unit
    {
      float* zb = W + ((size_t)zbh0 * 2048 + (zqt0 << 6) + (kt << 2)) * 2048 + zs0;
#pragma unroll
      for (int rr = 0; rr < 4; ++rr)
#pragma unroll
        for (int k = 0; k < 2; ++k) {
          int i = (int)threadIdx.x + k * 256;
          i = i < zc0 ? i : zc0 - 1;          // clamped duplicate (idempotent zero)
          ((f32x4*)(zb + (size_t)rr * 2048))[i] = zf4;
        }
      if (two_units) {
        float* zb1 = W + ((size_t)zbh1 * 2048 + (zqt1 << 6) + (kt << 2)) * 2048 + zs1;
#pragma unroll
        for (int rr = 0; rr < 4; ++rr)
#pragma unroll
          for (int k = 0; k < 2; ++k) {
            int i = (int)threadIdx.x + k * 256;
            i = i < zc1 ? i : zc1 - 1;
            ((f32x4*)(zb1 + (size_t)rr * 2048))[i] = zf4;
          }
      }
    }
    // drain the 8 loads (and any older stores); leave this kt's stores in flight
    if (two_units) asm volatile("s_waitcnt vmcnt(16)" ::: "memory");
    else           asm volatile("s_waitcnt vmcnt(8)" ::: "memory");
    __builtin_amdgcn_s_barrier();
#pragma unroll
    for (int ks = 0; ks < 2; ++ks) {
      h8 a[4], bb[4];
#pragma unroll
      for (int mi = 0; mi < 4; ++mi) {
        int row = wr * 64 + mi * 16 + l15;
        a[mi] = *(const h8*)((const char*)As + row * 128 + ((ks * 64 + g * 16) ^ ((row & 7) << 4)));
      }
#pragma unroll
      for (int ni = 0; ni < 4; ++ni) {
        int row = wc * 64 + ni * 16 + l15;
        bb[ni] = *(const h8*)((const char*)Bs + row * 128 + ((ks * 64 + g * 16) ^ ((row & 7) << 4)));
      }
#pragma unroll
      for (int mi = 0; mi < 4; ++mi)
#pragma unroll
        for (int ni = 0; ni < 4; ++ni)
          acc[mi][ni] = MFMA(a[mi], bb[ni], acc[mi][ni]);
    }
  }

  int part = nt >> 3;                 // 0=q 1=k 2=v
  int pc0 = (nt & 7) << 7;            // col base within part [0,1024)
  int b = (int)(m0 >> 11);
  int lbase = (int)(m0 & 2047);
  if (part < 2) {
    half_t* dst = part == 0 ? Qb : Kb;
#pragma unroll
    for (int mi = 0; mi < 4; ++mi)
#pragma unroll
      for (int ni = 0; ni < 4; ++ni)
#pragma unroll
        for (int r = 0; r < 4; ++r) {
          int pcol = pc0 + wc * 64 + ni * 16 + l15;
          int h = pcol >> 6, dh = pcol & 63;
          int l = lbase + wr * 64 + mi * 16 + g * 4 + r;
          dst[(((size_t)(b * 16 + h)) * 2048 + l) * 64 + dh] = (half_t)acc[mi][ni][r];
        }
  } else {
    // transpose 128x128 tile in LDS (pad row to 136 halves), then coalesced Vt writes
    half_t* T = (half_t*)smem;
    __syncthreads();
#pragma unroll
    for (int mi = 0; mi < 4; ++mi)
#pragma unroll
      for (int ni = 0; ni < 4; ++ni) {
        int c = wc * 64 + ni * 16 + l15;
        int r0 = wr * 64 + mi * 16 + g * 4;
        h4 hv;
        hv[0] = (half_t)acc[mi][ni][0]; hv[1] = (half_t)acc[mi][ni][1];
        hv[2] = (half_t)acc[mi][ni][2]; hv[3] = (half_t)acc[mi][ni][3];
        *(h4*)((char*)T + c * 272 + r0 * 2) = hv;
      }
    __syncthreads();
    int c = threadIdx.x >> 1, hf = threadIdx.x & 1;
    int pcol = pc0 + c;
    int h = pcol >> 6, dh = pcol & 63;
    half_t* vdst = Vtb + ((size_t)(b * 16 + h) * 64 + dh) * 2048 + lbase + hf * 64;
#pragma unroll
    for (int i = 0; i < 8; ++i) {
      h8 v = *(const h8*)((const char*)T + c * 272 + hf * 128 + i * 16);
      *(h8*)(vdst + i * 8) = v;
    }
  }
}

// ---------- GEMM2: out = Oh @ Wo (fp32 out), double-buffered LDS ----------
__global__ __launch_bounds__(256) void gemm_out(const half_t* __restrict__ A,
                                                const half_t* __restrict__ Bt,
                                                float* __restrict__ C) {
  __shared__ __align__(16) half_t As[2][128 * 64];
  __shared__ __align__(16) half_t Bs[2][64 * 64];
  int bid = blockIdx.x;
  int nt = bid % 16, mt = bid / 16;
  size_t m0 = (size_t)mt * 128, n0 = (size_t)nt * 64;
  int lane = threadIdx.x & 63, wv = threadIdx.x >> 6;
  int l15 = lane & 15, g = lane >> 4;
  f32x4 acc[2][4] = {};

  int arow[4], ass[4], brow[2], bss[2];
#pragma unroll
  for (int i = 0; i < 4; ++i) {
    int slot = (wv * 4 + i) * 64 + lane;
    arow[i] = slot >> 3; ass[i] = (slot & 7) ^ (arow[i] & 7);
  }
#pragma unroll
  for (int i = 0; i < 2; ++i) {
    int slot = (wv * 2 + i) * 64 + lane;
    brow[i] = slot >> 3; bss[i] = (slot & 7) ^ (brow[i] & 7);
  }

  // prologue: stage kt=0 into buf 0
#pragma unroll
  for (int i = 0; i < 4; ++i)
    gload16(A + (m0 + arow[i]) * 1024 + ass[i] * 8, &As[0][(wv * 4 + i) * 512]);
#pragma unroll
  for (int i = 0; i < 2; ++i)
    gload16(Bt + (n0 + brow[i]) * 1024 + bss[i] * 8, &Bs[0][(wv * 2 + i) * 512]);

  for (int kt = 0; kt < 16; ++kt) {
    asm volatile("s_waitcnt vmcnt(0)" ::: "memory");
    __builtin_amdgcn_s_barrier();
    if (kt < 15) {  // prefetch kt+1 into the other buffer
      int nb = (kt + 1) & 1;
#pragma unroll
      for (int i = 0; i < 4; ++i)
        gload16(A + (m0 + arow[i]) * 1024 + (kt + 1) * 64 + ass[i] * 8,
                &As[nb][(wv * 4 + i) * 512]);
#pragma unroll
      for (int i = 0; i < 2; ++i)
        gload16(Bt + (n0 + brow[i]) * 1024 + (kt + 1) * 64 + bss[i] * 8,
                &Bs[nb][(wv * 2 + i) * 512]);
    }
    int buf = kt & 1;
#pragma unroll
    for (int ks = 0; ks < 2; ++ks) {
      h8 a[2], bb[4];
#pragma unroll
      for (int mi = 0; mi < 2; ++mi) {
        int row = wv * 32 + mi * 16 + l15;
        a[mi] = *(const h8*)((const char*)&As[buf][0] + row * 128 +
                             ((ks * 64 + g * 16) ^ ((row & 7) << 4)));
      }
#pragma unroll
      for (int ni = 0; ni < 4; ++ni) {
        int row = ni * 16 + l15;
        bb[ni] = *(const h8*)((const char*)&Bs[buf][0] + row * 128 +
                              ((ks * 64 + g * 16) ^ ((row & 7) << 4)));
      }
#pragma unroll
      for (int mi = 0; mi < 2; ++mi)
#pragma unroll
        for (int ni = 0; ni < 4; ++ni)
          acc[mi][ni] = MFMA(a[mi], bb[ni], acc[mi][ni]);
    }
  }
#pragma unroll
  for (int mi = 0; mi < 2; ++mi)
#pragma unroll
    for (int ni = 0; ni < 4; ++ni)
#pragma unroll
      for (int r = 0; r < 4; ++r)
        C[(m0 + wv * 32 + mi * 16 + g * 4 + r) * 1024 + n0 + ni * 16 + l15] = acc[mi][ni][r];
}

// ---------- attention helpers: LDS-free, fragments straight from global ----
// Swapped-operand QK^T: lane holds s[r] = S[key = mt*64 + ni*16 + g*4 + r][query].
template <bool MASKED>
__device__ __forceinline__ void passA_tile(const half_t* __restrict__ kt0,
                                           h8 aq0, h8 aq1, float scale,
                                           int mt, int query, int l15, int g,
                                           float& z) {
#pragma unroll
  for (int ni = 0; ni < 4; ++ni) {
    const half_t* kp = kt0 + (size_t)(ni * 16 + l15) * 64;
    h8 k0 = *(const h8*)(kp + g * 8);
    h8 k1 = *(const h8*)(kp + 32 + g * 8);
    f32x4 s = {0.f, 0.f, 0.f, 0.f};
    s = MFMA(k0, aq0, s);
    s = MFMA(k1, aq1, s);
    int key0 = mt * 64 + ni * 16 + g * 4;
#pragma unroll
    for (int r = 0; r < 4; ++r) {
      if (MASKED) {
        if (key0 + r <= query) z += __expf(s[r] * scale - 20.f);
      } else {
        z += __expf(s[r] * scale - 20.f);
      }
    }
  }
}

// Pass B tile: QK^T -> p (register h4 per ni) -> w stores -> PV with the
// k-slot permutation k-slot(g,e) <-> key (e>>2)*16 + g*4 + (e&3).
// V fragments read directly from global Vt rows (stride 2048 halves).
template <bool MASKED>
__device__ __forceinline__ void passB_tile(const half_t* __restrict__ kt0,
                                           const half_t* __restrict__ vt0,
                                           h8 aq0, h8 aq1, float scale,
                                           int mt, int query, int l15, int g,
                                           float rz, float* __restrict__ wrow,
                                           f32x4 oacc[4]) {
  h4 ph[4];
#pragma unroll
  for (int ni = 0; ni < 4; ++ni) {
    const half_t* kp = kt0 + (size_t)(ni * 16 + l15) * 64;
    h8 k0 = *(const h8*)(kp + g * 8);
    h8 k1 = *(const h8*)(kp + 32 + g * 8);
    f32x4 s = {0.f, 0.f, 0.f, 0.f};
    s = MFMA(k0, aq0, s);
    s = MFMA(k1, aq1, s);
    int key0 = mt * 64 + ni * 16 + g * 4;
    f32x4 pw;
#pragma unroll
    for (int r = 0; r < 4; ++r) {
      float p = __expf(s[r] * scale - 20.f) * rz;
      if (MASKED) p = (key0 + r <= query) ? p : 0.f;
      pw[r] = p;
      ph[ni][r] = (half_t)p;
    }
    *(f32x4*)(wrow + key0) = pw;
  }
  h8 pa0 = __builtin_shufflevector(ph[0], ph[1], 0, 1, 2, 3, 4, 5, 6, 7);
  h8 pa1 = __builtin_shufflevector(ph[2], ph[3], 0, 1, 2, 3, 4, 5, 6, 7);
#pragma unroll
  for (int nd = 0; nd < 4; ++nd) {
    const half_t* vp = vt0 + (size_t)(nd * 16 + l15) * 2048;
    h4 b00 = *(const h4*)(vp + g * 4);
    h4 b01 = *(const h4*)(vp + 16 + g * 4);
    h4 b10 = *(const h4*)(vp + 32 + g * 4);
    h4 b11 = *(const h4*)(vp + 48 + g * 4);
    h8 bv0 = __builtin_shufflevector(b00, b01, 0, 1, 2, 3, 4, 5, 6, 7);
    h8 bv1 = __builtin_shufflevector(b10, b11, 0, 1, 2, 3, 4, 5, 6, 7);
    oacc[nd] = MFMA(pa0, bv0, oacc[nd]);
    oacc[nd] = MFMA(pa1, bv1, oacc[nd]);
  }
}

// ---------- attention: one block per (bh, 64-row q-tile); 4 waves x 16 rows ----------
// LDS-free: no barriers, no staging; waves fully independent. K/V panels are
// L2-resident (512KB/bh, ~2MB/XCD). bh = bid&31 (XCD locality);
// qt = balmap(bid>>5) -> per-CU qt-sum 62 exactly (uniform load).
__global__ __launch_bounds__(256) void attn_kernel(const half_t* __restrict__ Qb,
                                                   const half_t* __restrict__ Kb,
                                                   const half_t* __restrict__ Vtb,
                                                   const float* __restrict__ tau,
                                                   float* __restrict__ W,
                                                   half_t* __restrict__ Oh) {
  int bid = blockIdx.x;
  int bh = bid & 31, qt = balmap(bid >> 5);
  int b = bh >> 4, h = bh & 15;
  int lane = threadIdx.x & 63, wv = threadIdx.x >> 6;
  int l15 = lane & 15, g = lane >> 4;
  float scale = 1.0f / (8.0f * tau[bh]);            // 1/(sqrt(64)*tau)
  int q0 = qt * 64;
  int rowbase = q0 + wv * 16;
  int query = rowbase + l15;                        // this lane's w row

  // Q fragments held in registers across both passes
  size_t qoff = ((size_t)bh * 2048 + query) * 64 + g * 8;
  h8 aq0 = *(const h8*)(Qb + qoff);
  h8 aq1 = *(const h8*)(Qb + qoff + 32);
  const half_t* kgb = Kb + (size_t)bh * 2048 * 64;
  const half_t* vgb = Vtb + (size_t)bh * 64 * 2048;

  // ---- pass A: row sums Z = sum exp(s-20) over causal cols ----
  float z = 0.f;
  for (int mt = 0; mt < qt; ++mt)
    passA_tile<false>(kgb + (size_t)mt * 64 * 64, aq0, aq1, scale, mt, query, l15, g, z);
  passA_tile<true>(kgb + (size_t)qt * 64 * 64, aq0, aq1, scale, qt, query, l15, g, z);

  // lanes l15, l15+16, l15+32, l15+48 hold partials of the same query row
  z += __shfl_xor(z, 16);
  z += __shfl_xor(z, 32);
  float rz = 1.0f / z;

  // ---- pass B: recompute S, write w, accumulate O = w @ V ----
  f32x4 oacc[4] = {{0,0,0,0},{0,0,0,0},{0,0,0,0},{0,0,0,0}};
  float* wrow = W + (size_t)bh * 2048 * 2048 + (size_t)query * 2048;
  for (int mt = 0; mt < qt; ++mt)
    passB_tile<false>(kgb + (size_t)mt * 64 * 64, vgb + mt * 64, aq0, aq1, scale,
                      mt, query, l15, g, rz, wrow, oacc);
  passB_tile<true>(kgb + (size_t)qt * 64 * 64, vgb + qt * 64, aq0, aq1, scale,
                   qt, query, l15, g, rz, wrow, oacc);

  // Oh [b*2048+l][h*64+dh] fp16
#pragma unroll
  for (int nd = 0; nd < 4; ++nd)
#pragma unroll
    for (int r = 0; r < 4; ++r) {
      int l = rowbase + g * 4 + r;
      Oh[((size_t)b * 2048 + l) * 1024 + h * 64 + nd * 16 + l15] = (half_t)oacc[nd][r];
    }
}

extern "C" void kernel_launch(void* const* d_in, const int* in_sizes, int n_in,
                              void* d_out, int out_size, void* d_ws, size_t ws_size,
                              hipStream_t stream) {
  const float* x    = (const float*)d_in[0];
  const float* tau  = (const float*)d_in[1];
  const float* Wqkv = (const float*)d_in[2];
  const float* Wo   = (const float*)d_in[3];
  float* out = (float*)d_out;
  float* w   = out + 4194304;  // [2,16,2048,2048] after [2,2048,1024]

  char* ws = (char*)d_ws;
  half_t* xh    = (half_t*)(ws);                       // 8 MB  [4096][1024]
  half_t* wqkvt = (half_t*)(ws + (8ull  << 20));       // 6 MB  [3072][1024]
  half_t* wot   = (half_t*)(ws + (14ull << 20));       // 2 MB  [1024][1024]
  half_t* Qb    = (half_t*)(ws + (16ull << 20));       // 8 MB  [32][2048][64]
  half_t* Kb    = (half_t*)(ws + (24ull << 20));       // 8 MB  [32][2048][64]
  half_t* Vtb   = (half_t*)(ws + (32ull << 20));       // 8 MB  [32][64][2048]
  half_t* Ohb   = (half_t*)(ws + (40ull << 20));       // 8 MB  [4096][1024]

  prep_kernel<<<2048, 256, 0, stream>>>(x, xh, Wqkv, wqkvt, Wo, wot);
  gemm_qkv<<<768, 256, 0, stream>>>(xh, wqkvt, Qb, Kb, Vtb, w);
  attn_kernel<<<1024, 256, 0, stream>>>(Qb, Kb, Vtb, tau, w, Ohb);
  gemm_out<<<512, 256, 0, stream>>>(Ohb, wot, out);
}

// Round 14
// 204.233 us; speedup vs baseline: 1.8293x; 1.8293x over previous
//
#include <hip/hip_runtime.h>

// ThermoMHA on MI355X (gfx950).  [R12 configuration — verified best, 204.3 us]
// Pipeline: prep (cvt x + transpose Wqkv/Wo fused) -> GEMM1 (128x128 m97-style
// tile, scatter to Q/K/Vt fp16, V via LDS transpose; upper-tri zeros of w
// streamed from the K-loop with COUNTED vmcnt so stores fly across barriers,
// fixed-count clamped-idempotent store scheme, per-CU-balanced unit map) ->
// attn (two-pass, QBLK=64 x 4 waves x 1024 blocks, swapped-operand QK^T
// D[key][query], dwordx4 w stores, register-PV via k-slot permutation,
// 2-phase prefetch, counted vmcnt, balanced qt map) -> GEMM2 (double-buffered
// LDS, one barrier/kt + vmcnt(0)-before-barrier, prefetch kt+1).
// All matmuls: v_mfma_f32_16x16x32_f16, fp32 accum. Softmax fp32 fixed shift
// exp(s-20) via __expf (R6: inline-asm exp2 fold measured harmful).
//
// Falsified alternatives (keep for posterity):
//  R3  nontemporal stores: +21us (write-through defeats L2 write coalescing)
//  R5  zeros in gemm_out: +6us (2 blocks/CU + per-kt vmcnt(0) drains)
//  R8  QBLK=128/8-wave: +24us (halved per-CU block TLP)
//  R10/R11 zeros in attn (epilogue/in-loop): +10-12us (attn latency-bound)
//  R13 LDS-free attn: +169us (uncoalesced per-lane frags, 4x L2 traffic)
//
// Balance map: r -> qt = r<16 ? r : (r<24 ? 39-r : 55-r). Residency sets
// {k, 8+k, 16+k, 24+k} sum to 62 exactly -> per-CU load uniform.

typedef _Float16 half_t;
typedef __attribute__((ext_vector_type(8))) _Float16 h8;
typedef __attribute__((ext_vector_type(4))) _Float16 h4;
typedef __attribute__((ext_vector_type(4))) float f32x4;

#define MFMA(a, b, c) __builtin_amdgcn_mfma_f32_16x16x32_f16(a, b, c, 0, 0, 0)

__device__ __forceinline__ void gload16(const void* g, void* l) {
  __builtin_amdgcn_global_load_lds((const __attribute__((address_space(1))) void*)g,
                                   (__attribute__((address_space(3))) void*)l, 16, 0, 0);
}

__device__ __forceinline__ int balmap(int r) {  // bijection [0,32)->[0,32)
  return (r < 16) ? r : ((r < 24) ? 39 - r : 55 - r);
}

// ---------- fused prep: cvt x (fp32->fp16) + transpose Wqkv, Wo ----------
__global__ __launch_bounds__(256) void prep_kernel(const float* __restrict__ x,
                                                   half_t* __restrict__ xh,
                                                   const float* __restrict__ Wqkv,
                                                   half_t* __restrict__ wqkvt,
                                                   const float* __restrict__ Wo,
                                                   half_t* __restrict__ wot) {
  int b = blockIdx.x;
  if (b >= 1024) {  // cvt x: 1048576 f32x4 over 1024 blocks
    int i = (b - 1024) * 256 + threadIdx.x;
    for (; i < 1048576; i += 262144) {
      f32x4 v = ((const f32x4*)x)[i];
      h4 o;
      o[0] = (half_t)v[0]; o[1] = (half_t)v[1]; o[2] = (half_t)v[2]; o[3] = (half_t)v[3];
      ((h4*)xh)[i] = o;
    }
    return;
  }
  __shared__ float t[64][65];
  int yy = b >> 4;
  const float* in;
  half_t* out;
  int C, c0;
  if (yy < 48) { in = Wqkv; out = wqkvt; C = 3072; c0 = yy * 64; }
  else         { in = Wo;   out = wot;   C = 1024; c0 = (yy - 48) * 64; }
  int r0 = (b & 15) * 64;
  for (int i = threadIdx.x; i < 4096; i += 256) {
    int rr = i >> 6, cc = i & 63;
    t[rr][cc] = in[(size_t)(r0 + rr) * C + (c0 + cc)];
  }
  __syncthreads();
  for (int i = threadIdx.x; i < 4096; i += 256) {
    int rr = i >> 6, cc = i & 63;
    out[(size_t)(c0 + rr) * 1024 + (r0 + cc)] = (half_t)t[cc][rr];
  }
}

// ---------- GEMM1: qkv = xh @ Wqkv (128x128 tile, 4 waves each 64x64).
// Scatters to Q [bh][l][dh], K [bh][l][dh], Vt [bh][dh][l] (via LDS transpose).
// Zero-stream: per kt, [barrier; 8 gload_lds; S zero-stores; vmcnt(S);
// barrier; MFMA] -- stores stay in flight across the barrier and drain under
// the NEXT iteration's wait. S block-uniform in {8,16}. ----------
__global__ __launch_bounds__(256) void gemm_qkv(const half_t* __restrict__ A,
                                                const half_t* __restrict__ Bt,
                                                half_t* __restrict__ Qb, half_t* __restrict__ Kb,
                                                half_t* __restrict__ Vtb,
                                                float* __restrict__ W) {
  __shared__ __align__(16) char smem[34816];  // mainloop: As 16K + Bs 16K; epi: T 34K
  half_t* As = (half_t*)smem;
  half_t* Bs = As + 8192;
  int bid = blockIdx.x;
  int nt = bid % 24, mt = bid / 24;
  size_t m0 = (size_t)mt * 128, n0 = (size_t)nt * 128;
  int lane = threadIdx.x & 63, wv = threadIdx.x >> 6;
  int wr = wv >> 1, wc = wv & 1;
  int l15 = lane & 15, g = lane >> 4;
  f32x4 acc[4][4] = {};
  f32x4 zf4 = {0.f, 0.f, 0.f, 0.f};

  // zero-stream unit geometry (uniform per block)
  int zbh0 = bid & 31, zqt0 = balmap(bid >> 5);
  int zs0 = (zqt0 + 1) << 6;          // col start (always <= 1536 -> zc0 >= 128)
  int zc0 = (2048 - zs0) >> 2;        // f32x4 count per row
  int u1 = bid + 768;
  int zbh1 = u1 & 31, zqt1 = balmap(u1 >> 5);
  int zs1 = (zqt1 + 1) << 6;
  int zc1 = (2048 - zs1) >> 2;
  bool two_units = (bid < 256) && (zc1 > 0);

  for (int kt = 0; kt < 16; ++kt) {
    __builtin_amdgcn_s_barrier();     // prev MFMA done reading LDS (loads drained last iter)
#pragma unroll
    for (int i = 0; i < 4; ++i) {  // As: 16 chunks of 1KB
      int ch = wv * 4 + i;
      int slot = ch * 64 + lane;
      int row = slot >> 3, s = slot & 7, ss = s ^ (row & 7);
      gload16(A + (m0 + row) * 1024 + kt * 64 + ss * 8, As + ch * 512);
    }
#pragma unroll
    for (int i = 0; i < 4; ++i) {  // Bs: 16 chunks of 1KB
      int ch = wv * 4 + i;
      int slot = ch * 64 + lane;
      int row = slot >> 3, s = slot & 7, ss = s ^ (row & 7);
      gload16(Bt + (n0 + row) * 1024 + kt * 64 + ss * 8, Bs + ch * 512);
    }
    // zero stores: rows kt*4..kt*4+3 of each unit, fixed 8 stores/thread/unit
    {
      float* zb = W + ((size_t)zbh0 * 2048 + (zqt0 << 6) + (kt << 2)) * 2048 + zs0;
#pragma unroll
      for (int rr = 0; rr < 4; ++rr)
#pragma unroll
        for (int k = 0; k < 2; ++k) {
          int i = (int)threadIdx.x + k * 256;
          i = i < zc0 ? i : zc0 - 1;          // clamped duplicate (idempotent zero)
          ((f32x4*)(zb + (size_t)rr * 2048))[i] = zf4;
        }
      if (two_units) {
        float* zb1 = W + ((size_t)zbh1 * 2048 + (zqt1 << 6) + (kt << 2)) * 2048 + zs1;
#pragma unroll
        for (int rr = 0; rr < 4; ++rr)
#pragma unroll
          for (int k = 0; k < 2; ++k) {
            int i = (int)threadIdx.x + k * 256;
            i = i < zc1 ? i : zc1 - 1;
            ((f32x4*)(zb1 + (size_t)rr * 2048))[i] = zf4;
          }
      }
    }
    // drain the 8 loads (and any older stores); leave this kt's stores in flight
    if (two_units) asm volatile("s_waitcnt vmcnt(16)" ::: "memory");
    else           asm volatile("s_waitcnt vmcnt(8)" ::: "memory");
    __builtin_amdgcn_s_barrier();
#pragma unroll
    for (int ks = 0; ks < 2; ++ks) {
      h8 a[4], bb[4];
#pragma unroll
      for (int mi = 0; mi < 4; ++mi) {
        int row = wr * 64 + mi * 16 + l15;
        a[mi] = *(const h8*)((const char*)As + row * 128 + ((ks * 64 + g * 16) ^ ((row & 7) << 4)));
      }
#pragma unroll
      for (int ni = 0; ni < 4; ++ni) {
        int row = wc * 64 + ni * 16 + l15;
        bb[ni] = *(const h8*)((const char*)Bs + row * 128 + ((ks * 64 + g * 16) ^ ((row & 7) << 4)));
      }
#pragma unroll
      for (int mi = 0; mi < 4; ++mi)
#pragma unroll
        for (int ni = 0; ni < 4; ++ni)
          acc[mi][ni] = MFMA(a[mi], bb[ni], acc[mi][ni]);
    }
  }

  int part = nt >> 3;                 // 0=q 1=k 2=v
  int pc0 = (nt & 7) << 7;            // col base within part [0,1024)
  int b = (int)(m0 >> 11);
  int lbase = (int)(m0 & 2047);
  if (part < 2) {
    half_t* dst = part == 0 ? Qb : Kb;
#pragma unroll
    for (int mi = 0; mi < 4; ++mi)
#pragma unroll
      for (int ni = 0; ni < 4; ++ni)
#pragma unroll
        for (int r = 0; r < 4; ++r) {
          int pcol = pc0 + wc * 64 + ni * 16 + l15;
          int h = pcol >> 6, dh = pcol & 63;
          int l = lbase + wr * 64 + mi * 16 + g * 4 + r;
          dst[(((size_t)(b * 16 + h)) * 2048 + l) * 64 + dh] = (half_t)acc[mi][ni][r];
        }
  } else {
    // transpose 128x128 tile in LDS (pad row to 136 halves), then coalesced Vt writes
    half_t* T = (half_t*)smem;
    __syncthreads();
#pragma unroll
    for (int mi = 0; mi < 4; ++mi)
#pragma unroll
      for (int ni = 0; ni < 4; ++ni) {
        int c = wc * 64 + ni * 16 + l15;
        int r0 = wr * 64 + mi * 16 + g * 4;
        h4 hv;
        hv[0] = (half_t)acc[mi][ni][0]; hv[1] = (half_t)acc[mi][ni][1];
        hv[2] = (half_t)acc[mi][ni][2]; hv[3] = (half_t)acc[mi][ni][3];
        *(h4*)((char*)T + c * 272 + r0 * 2) = hv;
      }
    __syncthreads();
    int c = threadIdx.x >> 1, hf = threadIdx.x & 1;
    int pcol = pc0 + c;
    int h = pcol >> 6, dh = pcol & 63;
    half_t* vdst = Vtb + ((size_t)(b * 16 + h) * 64 + dh) * 2048 + lbase + hf * 64;
#pragma unroll
    for (int i = 0; i < 8; ++i) {
      h8 v = *(const h8*)((const char*)T + c * 272 + hf * 128 + i * 16);
      *(h8*)(vdst + i * 8) = v;
    }
  }
}

// ---------- GEMM2: out = Oh @ Wo (fp32 out), double-buffered LDS ----------
// 512 blocks = 2/CU (thin TLP) -> hide the 6-load L2 latency via dbuf:
// per kt: [vmcnt(0) (own loads landed; full compute phase in flight);
// barrier; prefetch kt+1 -> buf^1; compute buf]. One barrier per kt.
__global__ __launch_bounds__(256) void gemm_out(const half_t* __restrict__ A,
                                                const half_t* __restrict__ Bt,
                                                float* __restrict__ C) {
  __shared__ __align__(16) half_t As[2][128 * 64];
  __shared__ __align__(16) half_t Bs[2][64 * 64];
  int bid = blockIdx.x;
  int nt = bid % 16, mt = bid / 16;
  size_t m0 = (size_t)mt * 128, n0 = (size_t)nt * 64;
  int lane = threadIdx.x & 63, wv = threadIdx.x >> 6;
  int l15 = lane & 15, g = lane >> 4;
  f32x4 acc[2][4] = {};

  int arow[4], ass[4], brow[2], bss[2];
#pragma unroll
  for (int i = 0; i < 4; ++i) {
    int slot = (wv * 4 + i) * 64 + lane;
    arow[i] = slot >> 3; ass[i] = (slot & 7) ^ (arow[i] & 7);
  }
#pragma unroll
  for (int i = 0; i < 2; ++i) {
    int slot = (wv * 2 + i) * 64 + lane;
    brow[i] = slot >> 3; bss[i] = (slot & 7) ^ (brow[i] & 7);
  }

  // prologue: stage kt=0 into buf 0
#pragma unroll
  for (int i = 0; i < 4; ++i)
    gload16(A + (m0 + arow[i]) * 1024 + ass[i] * 8, &As[0][(wv * 4 + i) * 512]);
#pragma unroll
  for (int i = 0; i < 2; ++i)
    gload16(Bt + (n0 + brow[i]) * 1024 + bss[i] * 8, &Bs[0][(wv * 2 + i) * 512]);

  for (int kt = 0; kt < 16; ++kt) {
    asm volatile("s_waitcnt vmcnt(0)" ::: "memory");
    __builtin_amdgcn_s_barrier();
    if (kt < 15) {  // prefetch kt+1 into the other buffer
      int nb = (kt + 1) & 1;
#pragma unroll
      for (int i = 0; i < 4; ++i)
        gload16(A + (m0 + arow[i]) * 1024 + (kt + 1) * 64 + ass[i] * 8,
                &As[nb][(wv * 4 + i) * 512]);
#pragma unroll
      for (int i = 0; i < 2; ++i)
        gload16(Bt + (n0 + brow[i]) * 1024 + (kt + 1) * 64 + bss[i] * 8,
                &Bs[nb][(wv * 2 + i) * 512]);
    }
    int buf = kt & 1;
#pragma unroll
    for (int ks = 0; ks < 2; ++ks) {
      h8 a[2], bb[4];
#pragma unroll
      for (int mi = 0; mi < 2; ++mi) {
        int row = wv * 32 + mi * 16 + l15;
        a[mi] = *(const h8*)((const char*)&As[buf][0] + row * 128 +
                             ((ks * 64 + g * 16) ^ ((row & 7) << 4)));
      }
#pragma unroll
      for (int ni = 0; ni < 4; ++ni) {
        int row = ni * 16 + l15;
        bb[ni] = *(const h8*)((const char*)&Bs[buf][0] + row * 128 +
                              ((ks * 64 + g * 16) ^ ((row & 7) << 4)));
      }
#pragma unroll
      for (int mi = 0; mi < 2; ++mi)
#pragma unroll
        for (int ni = 0; ni < 4; ++ni)
          acc[mi][ni] = MFMA(a[mi], bb[ni], acc[mi][ni]);
    }
  }
#pragma unroll
  for (int mi = 0; mi < 2; ++mi)
#pragma unroll
    for (int ni = 0; ni < 4; ++ni)
#pragma unroll
      for (int r = 0; r < 4; ++r)
        C[(m0 + wv * 32 + mi * 16 + g * 4 + r) * 1024 + n0 + ni * 16 + l15] = acc[mi][ni][r];
}

// ---------- attention helpers (swapped-operand QK^T: D[key][query]) ----------
template <bool MASKED>
__device__ __forceinline__ void passA_tile(const half_t* kcur, h8 aq0, h8 aq1, float scale,
                                           int mt, int query, int l15, int g,
                                           float& z) {
#pragma unroll
  for (int ni = 0; ni < 4; ++ni) {
    int krow = ni * 16 + l15;
    const char* kp = (const char*)kcur + krow * 128;
    int sw = (krow & 7) << 4;
    h8 k0 = *(const h8*)(kp + ((g * 16) ^ sw));
    h8 k1 = *(const h8*)(kp + ((64 + g * 16) ^ sw));
    f32x4 s = {0.f, 0.f, 0.f, 0.f};
    s = MFMA(k0, aq0, s);
    s = MFMA(k1, aq1, s);
    int key0 = mt * 64 + ni * 16 + g * 4;
#pragma unroll
    for (int r = 0; r < 4; ++r) {
      if (MASKED) {
        if (key0 + r <= query) z += __expf(s[r] * scale - 20.f);
      } else {
        z += __expf(s[r] * scale - 20.f);
      }
    }
  }
}

// Pass B tile: QK^T -> p (register h4 per ni) -> w stores -> PV with the
// k-slot permutation k-slot(g,e) <-> key (e>>2)*16 + g*4 + (e&3).
template <bool MASKED>
__device__ __forceinline__ void passB_tile(const half_t* kcur, const half_t* vcur,
                                           h8 aq0, h8 aq1, float scale,
                                           int mt, int query, int l15, int g,
                                           float rz, float* __restrict__ wrow,
                                           f32x4 oacc[4]) {
  h4 ph[4];
#pragma unroll
  for (int ni = 0; ni < 4; ++ni) {
    int krow = ni * 16 + l15;
    const char* kp = (const char*)kcur + krow * 128;
    int sw = (krow & 7) << 4;
    h8 k0 = *(const h8*)(kp + ((g * 16) ^ sw));
    h8 k1 = *(const h8*)(kp + ((64 + g * 16) ^ sw));
    f32x4 s = {0.f, 0.f, 0.f, 0.f};
    s = MFMA(k0, aq0, s);
    s = MFMA(k1, aq1, s);
    int key0 = mt * 64 + ni * 16 + g * 4;
    f32x4 pw;
#pragma unroll
    for (int r = 0; r < 4; ++r) {
      float p = __expf(s[r] * scale - 20.f) * rz;
      if (MASKED) p = (key0 + r <= query) ? p : 0.f;
      pw[r] = p;
      ph[ni][r] = (half_t)p;
    }
    *(f32x4*)(wrow + key0) = pw;
  }
  h8 pa0 = __builtin_shufflevector(ph[0], ph[1], 0, 1, 2, 3, 4, 5, 6, 7);
  h8 pa1 = __builtin_shufflevector(ph[2], ph[3], 0, 1, 2, 3, 4, 5, 6, 7);
#pragma unroll
  for (int nd = 0; nd < 4; ++nd) {
    int vrow = nd * 16 + l15;
    const char* vp = (const char*)vcur + vrow * 128;
    int swv = (vrow & 7) << 4;
    h4 b00 = *(const h4*)(vp + ((g * 8) ^ swv));
    h4 b01 = *(const h4*)(vp + ((32 + g * 8) ^ swv));
    h4 b10 = *(const h4*)(vp + ((64 + g * 8) ^ swv));
    h4 b11 = *(const h4*)(vp + ((96 + g * 8) ^ swv));
    h8 bv0 = __builtin_shufflevector(b00, b01, 0, 1, 2, 3, 4, 5, 6, 7);
    h8 bv1 = __builtin_shufflevector(b10, b11, 0, 1, 2, 3, 4, 5, 6, 7);
    oacc[nd] = MFMA(pa0, bv0, oacc[nd]);
    oacc[nd] = MFMA(pa1, bv1, oacc[nd]);
  }
}

// ---------- attention: one block per (bh, 64-row q-tile); 4 waves x 16 rows ----------
// bid decode: bh = bid&31 (XCD locality); qt = balmap(bid>>5) so each CU's 4
// resident blocks have qt-sum 62 exactly -> uniform per-CU load.
// 2-phase pipeline: raw s_barrier + counted vmcnt; per tile:
//   [wait vmcnt(N); barrier; prefetch t+1 -> buf^1; compute buf]
// N=0 pass A (only loads in flight); N=4 pass B (drain 4 prefetch loads,
// leave the previous tile's 4 w-stores in flight).
__global__ __launch_bounds__(256) void attn_kernel(const half_t* __restrict__ Qb,
                                                   const half_t* __restrict__ Kb,
                                                   const half_t* __restrict__ Vtb,
                                                   const float* __restrict__ tau,
                                                   float* __restrict__ W,
                                                   half_t* __restrict__ Oh) {
  __shared__ __align__(16) half_t Ks[2][64 * 64];   // [key][dh], swizzled, dbuf
  __shared__ __align__(16) half_t Vs[2][64 * 64];   // [dh][key], swizzled, dbuf
  __shared__ half_t ldspad[4096];                   // occupancy pin: 40KB/block -> 4 blocks/CU
  int bid = blockIdx.x;
  int bh = bid & 31, qt = balmap(bid >> 5);
  int b = bh >> 4, h = bh & 15;
  int lane = threadIdx.x & 63, wv = threadIdx.x >> 6;
  int l15 = lane & 15, g = lane >> 4;
  float tau0 = tau[bh];
  if (tau0 == -12345.0f) ldspad[threadIdx.x] = 0;   // never true (tau in [0.5,1.5)); keeps pad live
  float scale = 1.0f / (8.0f * tau0);               // 1/(sqrt(64)*tau)
  int q0 = qt * 64;
  int rowbase = q0 + wv * 16;
  int query = rowbase + l15;                        // this lane's w row

  // Q fragments held in registers across both passes
  size_t qoff = ((size_t)bh * 2048 + rowbase + l15) * 64 + g * 8;
  h8 aq0 = *(const h8*)(Qb + qoff);
  h8 aq1 = *(const h8*)(Qb + qoff + 32);
  const half_t* kgb = Kb + (size_t)bh * 2048 * 64;
  const half_t* vgb = Vtb + (size_t)bh * 64 * 2048;

  // staging geometry: wave wv stages chunks ch = wv*2+i, i=0..1 (1KB each)
  int ch0 = wv * 2;
  int slot0 = ch0 * 64 + lane, slot1 = slot0 + 64;
  int krow0 = slot0 >> 3, kss0 = (slot0 & 7) ^ (krow0 & 7);
  int krow1 = slot1 >> 3, kss1 = (slot1 & 7) ^ (krow1 & 7);

  // ---- pass A: row sums Z = sum exp(s-20) over causal cols ----
  // prologue: stage K tile 0 into buf 0
  gload16(kgb + (size_t)krow0 * 64 + kss0 * 8, &Ks[0][ch0 * 512]);
  gload16(kgb + (size_t)krow1 * 64 + kss1 * 8, &Ks[0][ch0 * 512 + 512]);

  float z = 0.f;
  for (int mt = 0; mt <= qt; ++mt) {
    asm volatile("s_waitcnt vmcnt(0)" ::: "memory");
    __builtin_amdgcn_s_barrier();
    if (mt < qt) {  // prefetch K tile mt+1 into the other buffer
      const half_t* src = kgb + (size_t)(mt + 1) * 64 * 64;
      half_t* dst = &Ks[(mt + 1) & 1][ch0 * 512];
      gload16(src + (size_t)krow0 * 64 + kss0 * 8, dst);
      gload16(src + (size_t)krow1 * 64 + kss1 * 8, dst + 512);
    }
    const half_t* kcur = &Ks[mt & 1][0];
    if (mt < qt)
      passA_tile<false>(kcur, aq0, aq1, scale, mt, query, l15, g, z);
    else
      passA_tile<true>(kcur, aq0, aq1, scale, mt, query, l15, g, z);
  }
  // lanes l15, l15+16, l15+32, l15+48 hold partials of the same query row
  z += __shfl_xor(z, 16);
  z += __shfl_xor(z, 32);
  float rz = 1.0f / z;

  // ---- pass B: recompute S, write w, accumulate O = w @ V ----
  // barrier: all waves done reading Ks from pass A before restaging buf 0
  __builtin_amdgcn_s_barrier();
  gload16(kgb + (size_t)krow0 * 64 + kss0 * 8, &Ks[0][ch0 * 512]);
  gload16(kgb + (size_t)krow1 * 64 + kss1 * 8, &Ks[0][ch0 * 512 + 512]);
  gload16(vgb + (size_t)krow0 * 2048 + kss0 * 8, &Vs[0][ch0 * 512]);
  gload16(vgb + (size_t)krow1 * 2048 + kss1 * 8, &Vs[0][ch0 * 512 + 512]);

  f32x4 oacc[4] = {{0,0,0,0},{0,0,0,0},{0,0,0,0},{0,0,0,0}};
  float* wrow = W + (size_t)bh * 2048 * 2048 + (size_t)query * 2048;
  for (int mt = 0; mt <= qt; ++mt) {
    if (mt == 0)
      asm volatile("s_waitcnt vmcnt(0)" ::: "memory");
    else
      asm volatile("s_waitcnt vmcnt(4)" ::: "memory");  // prev 4 w-stores may fly
    __builtin_amdgcn_s_barrier();
    if (mt < qt) {  // prefetch K+V tile mt+1 into the other buffer
      int nb = (mt + 1) & 1;
      const half_t* ksrc = kgb + (size_t)(mt + 1) * 64 * 64;
      const half_t* vsrc = vgb + (size_t)(mt + 1) * 64;
      gload16(ksrc + (size_t)krow0 * 64 + kss0 * 8, &Ks[nb][ch0 * 512]);
      gload16(ksrc + (size_t)krow1 * 64 + kss1 * 8, &Ks[nb][ch0 * 512 + 512]);
      gload16(vsrc + (size_t)krow0 * 2048 + kss0 * 8, &Vs[nb][ch0 * 512]);
      gload16(vsrc + (size_t)krow1 * 2048 + kss1 * 8, &Vs[nb][ch0 * 512 + 512]);
    }
    const half_t* kcur = &Ks[mt & 1][0];
    const half_t* vcur = &Vs[mt & 1][0];
    if (mt < qt)
      passB_tile<false>(kcur, vcur, aq0, aq1, scale, mt, query, l15, g, rz, wrow, oacc);
    else
      passB_tile<true>(kcur, vcur, aq0, aq1, scale, mt, query, l15, g, rz, wrow, oacc);
  }
  // Oh [b*2048+l][h*64+dh] fp16
#pragma unroll
  for (int nd = 0; nd < 4; ++nd)
#pragma unroll
    for (int r = 0; r < 4; ++r) {
      int l = rowbase + g * 4 + r;
      Oh[((size_t)b * 2048 + l) * 1024 + h * 64 + nd * 16 + l15] = (half_t)oacc[nd][r];
    }
}

extern "C" void kernel_launch(void* const* d_in, const int* in_sizes, int n_in,
                              void* d_out, int out_size, void* d_ws, size_t ws_size,
                              hipStream_t stream) {
  const float* x    = (const float*)d_in[0];
  const float* tau  = (const float*)d_in[1];
  const float* Wqkv = (const float*)d_in[2];
  const float* Wo   = (const float*)d_in[3];
  float* out = (float*)d_out;
  float* w   = out + 4194304;  // [2,16,2048,2048] after [2,2048,1024]

  char* ws = (char*)d_ws;
  half_t* xh    = (half_t*)(ws);                       // 8 MB  [4096][1024]
  half_t* wqkvt = (half_t*)(ws + (8ull  << 20));       // 6 MB  [3072][1024]
  half_t* wot   = (half_t*)(ws + (14ull << 20));       // 2 MB  [1024][1024]
  half_t* Qb    = (half_t*)(ws + (16ull << 20));       // 8 MB  [32][2048][64]
  half_t* Kb    = (half_t*)(ws + (24ull << 20));       // 8 MB  [32][2048][64]
  half_t* Vtb   = (half_t*)(ws + (32ull << 20));       // 8 MB  [32][64][2048]
  half_t* Ohb   = (half_t*)(ws + (40ull << 20));       // 8 MB  [4096][1024]

  prep_kernel<<<2048, 256, 0, stream>>>(x, xh, Wqkv, wqkvt, Wo, wot);
  gemm_qkv<<<768, 256, 0, stream>>>(xh, wqkvt, Qb, Kb, Vtb, w);
  attn_kernel<<<1024, 256, 0, stream>>>(Qb, Kb, Vtb, tau, w, Ohb);
  gemm_out<<<512, 256, 0, stream>>>(Ohb, wot, out);
}